// Round 1
// baseline (18373.615 us; speedup 1.0000x reference)
//
#include <hip/hip_runtime.h>
#include <stdint.h>

// Problem dims
#define BATCH 128
#define SEQ   512
#define DIN   256
#define HID   512
#define KA    768   // D+H   (layer0 K)
#define KB    1024  // 2H    (layer1 K)
#define LDKA  776   // padded LDS K-stride (bank-conflict pad, keeps 16B align)
#define LDKB  1032
#define NWG_A 32
#define NWG   64
#define TPB   256
#define NSLOT 513   // pipeline slots: h0(p) for p<512, h1(p-1) for p>=1
#define OUTD  1275

typedef __attribute__((ext_vector_type(8))) short bf16x8;  // 8 bf16 = 4 VGPRs (MFMA frag)
typedef __attribute__((ext_vector_type(4))) float f32x4;

static __device__ __forceinline__ unsigned short f2bf(float f) {
  unsigned int u = __builtin_bit_cast(unsigned int, f);
  u += 0x7FFFu + ((u >> 16) & 1u);          // RNE
  return (unsigned short)(u >> 16);
}
static __device__ __forceinline__ float sigmoidf_fast(float v) {
  float e = __expf(-fabsf(v));
  float s = 1.0f / (1.0f + e);
  return v >= 0.0f ? s : 1.0f - s;
}
static __device__ __forceinline__ float tanhf_fast(float v) {
  float e = __expf(-2.0f * fabsf(v));
  float t = (1.0f - e) / (1.0f + e);
  return v >= 0.0f ? t : -t;
}

// Persistent 2-layer LSTM. 64 WGs: wg<32 own 16 units of layer0, wg>=32 own 16
// units of layer1. Weights (own 64 gate-columns, transposed, bf16) persist in
// LDS. Cell state persists in VGPRs. h0/h1 cross WGs via double-buffered bf16
// global arrays; one software grid barrier per slot.
__global__ __launch_bounds__(TPB, 1) void lstm_persistent(
    const float* __restrict__ x, const float* __restrict__ W0,
    const float* __restrict__ b0, const float* __restrict__ W1,
    const float* __restrict__ b1, unsigned int* __restrict__ bar_cnt,
    unsigned short* __restrict__ h0buf, unsigned short* __restrict__ h1buf,
    float* __restrict__ h1fin)
{
  __shared__ unsigned short smem[64 * LDKB];  // 132096 B (layer0 WGs use LDKA stride)

  const int tid  = threadIdx.x;
  const int wgid = blockIdx.x;
  const bool isA = (wgid < NWG_A);
  const int unit0 = (isA ? wgid : (wgid - NWG_A)) << 4;  // 16 units per WG
  const int lane = tid & 63;
  const int wv   = tid >> 6;       // 4 waves
  const int Mh   = wv & 1;         // batch half (64 rows)
  const int Nh   = (wv >> 1) & 1;  // unit half (8 units)
  const int c15  = lane & 15;
  const int q    = lane >> 4;      // 0..3
  const int s    = (lane >> 3) & 1;// 0: i/g column, 1: f/o column
  const int u    = lane & 7;       // unit within half
  const int myunit = unit0 + Nh * 8 + u;

  // ---- stage weights -> LDS, transposed to [col][k], bf16 ----
  // LDS col c in [0,64): c = nh*32 + t*16 + s*8 + u ; gate = t*2+s (i,f,g,o)
  {
    const int K = isA ? KA : KB;
    const int ldk = isA ? LDKA : LDKB;
    const float* W = isA ? W0 : W1;
    for (int idx = tid; idx < 64 * K; idx += TPB) {
      int cc = idx & 63;
      int kk = idx >> 6;
      int gate = (((cc >> 4) & 1) << 1) | ((cc >> 3) & 1);
      int gcol = gate * HID + unit0 + (cc >> 5) * 8 + (cc & 7);
      smem[cc * ldk + kk] = f2bf(W[(size_t)kk * 2048 + gcol]);
    }
  }

  // per-lane bias for the two packed tiles (t=0:[i|f], t=1:[g|o])
  const float* bv = isA ? b0 : b1;
  float bias_t[2];
#pragma unroll
  for (int t = 0; t < 2; ++t)
    bias_t[t] = bv[(t * 2 + s) * HID + myunit];

  f32x4 cst[4];  // cell state: rows (Mh*64+mi*16+q*4+r) x col myunit; valid on s==0 lanes
#pragma unroll
  for (int mi = 0; mi < 4; ++mi) cst[mi] = (f32x4){0.f, 0.f, 0.f, 0.f};

  const int colbase = Nh * 32;

  __syncthreads();

  for (int p = 0; p < NSLOT; ++p) {
    const unsigned short* h0rd = h0buf + ((p + 1) & 1) * (BATCH * HID);  // h0(p-1)

    if (isA) {
      if (p < SEQ) {
        // z0(p) = [x_p, h0(p-1)] @ W0 + b0  -> gates -> h0(p)
        f32x4 acc[4][2];
#pragma unroll
        for (int mi = 0; mi < 4; ++mi)
#pragma unroll
          for (int t = 0; t < 2; ++t)
            acc[mi][t] = (f32x4){bias_t[t], bias_t[t], bias_t[t], bias_t[t]};

        // x part (k 0..255), fp32 load + cvt
#pragma unroll 2
        for (int kt = 0; kt < 8; ++kt) {
          bf16x8 bfr[2];
#pragma unroll
          for (int t = 0; t < 2; ++t)
            bfr[t] = *(const bf16x8*)&smem[(colbase + t * 16 + c15) * LDKA + kt * 32 + q * 8];
#pragma unroll
          for (int mi = 0; mi < 4; ++mi) {
            int row = Mh * 64 + mi * 16 + c15;
            const float* xp = x + ((size_t)row * SEQ + p) * DIN + kt * 32 + q * 8;
            f32x4 xa = *(const f32x4*)xp;
            f32x4 xb = *(const f32x4*)(xp + 4);
            bf16x8 af;
            af[0] = (short)f2bf(xa[0]); af[1] = (short)f2bf(xa[1]);
            af[2] = (short)f2bf(xa[2]); af[3] = (short)f2bf(xa[3]);
            af[4] = (short)f2bf(xb[0]); af[5] = (short)f2bf(xb[1]);
            af[6] = (short)f2bf(xb[2]); af[7] = (short)f2bf(xb[3]);
#pragma unroll
            for (int t = 0; t < 2; ++t)
              acc[mi][t] = __builtin_amdgcn_mfma_f32_16x16x32_bf16(af, bfr[t], acc[mi][t], 0, 0, 0);
          }
        }
        // h0 part (k 256..767)
#pragma unroll 2
        for (int kt = 8; kt < 24; ++kt) {
          bf16x8 bfr[2];
#pragma unroll
          for (int t = 0; t < 2; ++t)
            bfr[t] = *(const bf16x8*)&smem[(colbase + t * 16 + c15) * LDKA + kt * 32 + q * 8];
#pragma unroll
          for (int mi = 0; mi < 4; ++mi) {
            int row = Mh * 64 + mi * 16 + c15;
            bf16x8 af = *(const bf16x8*)&h0rd[(size_t)row * HID + (kt - 8) * 32 + q * 8];
#pragma unroll
            for (int t = 0; t < 2; ++t)
              acc[mi][t] = __builtin_amdgcn_mfma_f32_16x16x32_bf16(af, bfr[t], acc[mi][t], 0, 0, 0);
          }
        }
        // gates (pair i/f and g/o via shfl_xor 8) + write h0(p)
        unsigned short* h0wr = h0buf + (p & 1) * (BATCH * HID);
#pragma unroll
        for (int mi = 0; mi < 4; ++mi) {
#pragma unroll
          for (int r = 0; r < 4; ++r) {
            float a0 = acc[mi][0][r], a1 = acc[mi][1][r];
            float p0 = __shfl_xor(a0, 8);  // partner gate (f or i)
            float p1 = __shfl_xor(a1, 8);  // partner gate (o or g)
            if (s == 0) {
              float cn = sigmoidf_fast(p0) * cst[mi][r] + sigmoidf_fast(a0) * tanhf_fast(a1);
              cst[mi][r] = cn;
              float hn = sigmoidf_fast(p1) * tanhf_fast(cn);
              int row = Mh * 64 + mi * 16 + q * 4 + r;
              h0wr[(size_t)row * HID + myunit] = f2bf(hn);
            }
          }
        }
      }
    } else {
      if (p >= 1) {
        // z1(t) = [h0(t), h1(t-1)] @ W1 + b1, t = p-1 -> gates -> h1(t)
        const unsigned short* h1rd = h1buf + (p & 1) * (BATCH * HID);        // h1(p-2)
        unsigned short* h1wr = h1buf + ((p + 1) & 1) * (BATCH * HID);        // h1(p-1)
        f32x4 acc[4][2];
#pragma unroll
        for (int mi = 0; mi < 4; ++mi)
#pragma unroll
          for (int t = 0; t < 2; ++t)
            acc[mi][t] = (f32x4){bias_t[t], bias_t[t], bias_t[t], bias_t[t]};

#pragma unroll 2
        for (int kt = 0; kt < 16; ++kt) {  // h0(t) half
          bf16x8 bfr[2];
#pragma unroll
          for (int t = 0; t < 2; ++t)
            bfr[t] = *(const bf16x8*)&smem[(colbase + t * 16 + c15) * LDKB + kt * 32 + q * 8];
#pragma unroll
          for (int mi = 0; mi < 4; ++mi) {
            int row = Mh * 64 + mi * 16 + c15;
            bf16x8 af = *(const bf16x8*)&h0rd[(size_t)row * HID + kt * 32 + q * 8];
#pragma unroll
            for (int t = 0; t < 2; ++t)
              acc[mi][t] = __builtin_amdgcn_mfma_f32_16x16x32_bf16(af, bfr[t], acc[mi][t], 0, 0, 0);
          }
        }
#pragma unroll 2
        for (int kt = 16; kt < 32; ++kt) { // h1(t-1) half
          bf16x8 bfr[2];
#pragma unroll
          for (int t = 0; t < 2; ++t)
            bfr[t] = *(const bf16x8*)&smem[(colbase + t * 16 + c15) * LDKB + kt * 32 + q * 8];
#pragma unroll
          for (int mi = 0; mi < 4; ++mi) {
            int row = Mh * 64 + mi * 16 + c15;
            bf16x8 af = *(const bf16x8*)&h1rd[(size_t)row * HID + (kt - 16) * 32 + q * 8];
#pragma unroll
            for (int t = 0; t < 2; ++t)
              acc[mi][t] = __builtin_amdgcn_mfma_f32_16x16x32_bf16(af, bfr[t], acc[mi][t], 0, 0, 0);
          }
        }
#pragma unroll
        for (int mi = 0; mi < 4; ++mi) {
#pragma unroll
          for (int r = 0; r < 4; ++r) {
            float a0 = acc[mi][0][r], a1 = acc[mi][1][r];
            float p0 = __shfl_xor(a0, 8);
            float p1 = __shfl_xor(a1, 8);
            if (s == 0) {
              float cn = sigmoidf_fast(p0) * cst[mi][r] + sigmoidf_fast(a0) * tanhf_fast(a1);
              cst[mi][r] = cn;
              float hn = sigmoidf_fast(p1) * tanhf_fast(cn);
              int row = Mh * 64 + mi * 16 + q * 4 + r;
              h1wr[(size_t)row * HID + myunit] = f2bf(hn);
              if (p == NSLOT - 1) h1fin[(size_t)row * HID + myunit] = hn;
            }
          }
        }
      }
    }

    // ---- software grid barrier (monotonic counter, agent scope) ----
    __syncthreads();
    if (tid == 0) {
      __threadfence();  // release: push h writes device-visible
      __hip_atomic_fetch_add(bar_cnt, 1u, __ATOMIC_RELEASE, __HIP_MEMORY_SCOPE_AGENT);
      unsigned int target = (unsigned int)(p + 1) * NWG;
      while (__hip_atomic_load(bar_cnt, __ATOMIC_ACQUIRE, __HIP_MEMORY_SCOPE_AGENT) < target) {
        __builtin_amdgcn_s_sleep(1);
      }
    }
    __syncthreads();
    __threadfence();  // acquire side for all waves (invalidate stale cache)
  }
}

// out[b][o] = h1_final[b] . Wp[:,o] + bp[o]
__global__ __launch_bounds__(256) void proj_kernel(
    const float* __restrict__ h1, const float* __restrict__ Wp,
    const float* __restrict__ bp, float* __restrict__ out)
{
  int o = blockIdx.x * 256 + threadIdx.x;
  int b = blockIdx.y;
  if (o >= OUTD) return;
  const float* hr = h1 + (size_t)b * HID;
  float acc = bp[o];
#pragma unroll 8
  for (int k = 0; k < HID; ++k)
    acc = fmaf(hr[k], Wp[(size_t)k * OUTD + o], acc);
  out[(size_t)b * OUTD + o] = acc;
}

extern "C" void kernel_launch(void* const* d_in, const int* in_sizes, int n_in,
                              void* d_out, int out_size, void* d_ws, size_t ws_size,
                              hipStream_t stream) {
  const float* x  = (const float*)d_in[0];
  const float* W0 = (const float*)d_in[1];
  const float* b0 = (const float*)d_in[2];
  const float* W1 = (const float*)d_in[3];
  const float* b1 = (const float*)d_in[4];
  const float* Wp = (const float*)d_in[5];
  const float* bp = (const float*)d_in[6];
  float* out = (float*)d_out;

  char* ws = (char*)d_ws;
  unsigned int* cnt   = (unsigned int*)ws;                       // [0,4096): barrier counter
  unsigned short* h0b = (unsigned short*)(ws + 4096);            // 2x128x512 bf16 = 256 KB
  unsigned short* h1b = (unsigned short*)(ws + 4096 + 262144);   // 256 KB
  float* h1fin        = (float*)(ws + 4096 + 2 * 262144);        // 128x512 fp32 = 256 KB
  size_t zero_bytes = 4096 + 2 * 262144;  // counter + h buffers (h0(-1)=h1(-1)=0)

  hipMemsetAsync(d_ws, 0, zero_bytes, stream);
  hipLaunchKernelGGL(lstm_persistent, dim3(NWG), dim3(TPB), 0, stream,
                     x, W0, b0, W1, b1, cnt, h0b, h1b, h1fin);
  hipLaunchKernelGGL(proj_kernel, dim3((OUTD + 255) / 256, BATCH), dim3(256), 0, stream,
                     h1fin, Wp, bp, out);
}

// Round 2
// 6143.251 us; speedup vs baseline: 2.9909x; 2.9909x over previous
//
#include <hip/hip_runtime.h>
#include <stdint.h>

// Problem dims
#define BATCH 128
#define SEQ   512
#define DIN   256
#define HID   512
#define LDKA  776   // padded LDS K-stride (shorts), layer0 K=768
#define LDKB  1032  // layer1 K=1024
#define NWG_A 32
#define NWG   64
#define TPB   512   // 8 waves: wave = one 16-row M-tile
#define NSLOT 513
#define OUTD  1275

typedef __attribute__((ext_vector_type(8))) short bf16x8;
typedef __attribute__((ext_vector_type(8))) unsigned short ushort8;
typedef __attribute__((ext_vector_type(4))) float f32x4;

static __device__ __forceinline__ unsigned short f2bf(float f) {
  unsigned int u = __builtin_bit_cast(unsigned int, f);
  u += 0x7FFFu + ((u >> 16) & 1u);  // RNE
  return (unsigned short)(u >> 16);
}
static __device__ __forceinline__ float sigmoidf_fast(float v) {
  float e = __expf(-fabsf(v));
  float s = 1.0f / (1.0f + e);
  return v >= 0.0f ? s : 1.0f - s;
}
static __device__ __forceinline__ float tanhf_fast(float v) {
  float e = __expf(-2.0f * fabsf(v));
  float t = (1.0f - e) / (1.0f + e);
  return v >= 0.0f ? t : -t;
}

// Convert x to bf16 in MFMA-fragment order: xb[(((p*8+mi)*8+kt)*64+lane)*8],
// element j = x[row=mi*16+(lane&15)][k=kt*32+(lane>>4)*8+j] at step p.
__global__ __launch_bounds__(256) void xprep(const float* __restrict__ x,
                                             unsigned short* __restrict__ xb) {
  int p = blockIdx.x;
  int lane = threadIdx.x & 63;
  int g4 = threadIdx.x >> 6;
  int c15 = lane & 15, q = lane >> 4;
  for (int g = 0; g < 16; ++g) {
    int idx = g * 4 + g4;           // 0..63 = (mi,kt)
    int mi = idx >> 3, kt = idx & 7;
    int row = mi * 16 + c15;
    const float* src = x + ((size_t)row * SEQ + p) * DIN + kt * 32 + q * 8;
    f32x4 a = *(const f32x4*)src;
    f32x4 b = *(const f32x4*)(src + 4);
    bf16x8 v;
    v[0] = (short)f2bf(a[0]); v[1] = (short)f2bf(a[1]);
    v[2] = (short)f2bf(a[2]); v[3] = (short)f2bf(a[3]);
    v[4] = (short)f2bf(b[0]); v[5] = (short)f2bf(b[1]);
    v[6] = (short)f2bf(b[2]); v[7] = (short)f2bf(b[3]);
    *(bf16x8*)&xb[((((size_t)p * 8 + mi) * 8 + kt) * 64 + lane) * 8] = v;
  }
}

// Persistent 2-layer LSTM. 64 WGs x 512 thr. wg<32: 16 units of layer0;
// wg>=32: 16 units of layer1. Weights persist in LDS ([col][k] bf16, padded).
// Cell state in VGPRs. h0/h1 exchanged in fragment layout via global scratch;
// one software grid barrier per slot (relaxed poll + single acquire).
template <bool USE_XB>
__global__ __launch_bounds__(TPB) void lstm_persistent(
    const float* __restrict__ x, const unsigned short* __restrict__ xb,
    const float* __restrict__ W0, const float* __restrict__ b0,
    const float* __restrict__ W1, const float* __restrict__ b1,
    unsigned int* __restrict__ bar_cnt, unsigned short* __restrict__ h0buf,
    unsigned short* __restrict__ h1buf, float* __restrict__ h1fin)
{
  __shared__ unsigned short smem[64 * LDKB + 128 * 16];
  unsigned short* stage = &smem[64 * LDKB];  // 128 rows x 16 units

  const int tid  = threadIdx.x;
  const int wgid = blockIdx.x;
  const bool isA = (wgid < NWG_A);
  const int unit0 = (isA ? wgid : (wgid - NWG_A)) << 4;
  const int kt0   = unit0 >> 5;          // frag kt of this WG's unit block
  const int qbase = (unit0 >> 3) & 3;    // 0 or 2
  const int lane = tid & 63;
  const int wv   = tid >> 6;             // 0..7 = M-tile (rows wv*16+c15)
  const int c15  = lane & 15;
  const int q    = lane >> 4;
  const int s    = (lane >> 3) & 1;      // 0: i/g col, 1: f/o col
  const int u    = lane & 7;

  // ---- stage weights -> LDS, [col][k] bf16; col = Nh*32 + t*16 + s*8 + u ----
  {
    const int K = isA ? 768 : 1024;
    const int ldk = isA ? LDKA : LDKB;
    const float* W = isA ? W0 : W1;
    for (int idx = tid; idx < 64 * K; idx += TPB) {
      int cc = idx & 63;
      int kk = idx >> 6;
      int gate = (((cc >> 4) & 1) << 1) | ((cc >> 3) & 1);
      int gcol = gate * HID + unit0 + (cc >> 5) * 8 + (cc & 7);
      smem[cc * ldk + kk] = f2bf(W[(size_t)kk * 2048 + gcol]);
    }
  }

  const float* bv = isA ? b0 : b1;
  float bias_t[2][2];
#pragma unroll
  for (int Nh = 0; Nh < 2; ++Nh)
#pragma unroll
    for (int t = 0; t < 2; ++t)
      bias_t[Nh][t] = bv[(t * 2 + s) * HID + unit0 + Nh * 8 + u];

  f32x4 cst[2];  // cell state, rows wv*16+q*4+r, unit unit0+Nh*8+u (s==0 lanes)
#pragma unroll
  for (int Nh = 0; Nh < 2; ++Nh) cst[Nh] = (f32x4){0.f, 0.f, 0.f, 0.f};

  const int ldk = isA ? LDKA : LDKB;
  __syncthreads();

  for (int p = 0; p < NSLOT; ++p) {
    const unsigned short* h0rd = h0buf + ((p + 1) & 1) * (BATCH * HID);
    unsigned short* h0wr       = h0buf + (p & 1) * (BATCH * HID);
    const unsigned short* h1rd = h1buf + (p & 1) * (BATCH * HID);
    unsigned short* h1wr       = h1buf + ((p + 1) & 1) * (BATCH * HID);
    const bool active = isA ? (p < SEQ) : (p >= 1);

    f32x4 acc[2][2];
#pragma unroll
    for (int Nh = 0; Nh < 2; ++Nh)
#pragma unroll
      for (int t = 0; t < 2; ++t)
        acc[Nh][t] = (f32x4){bias_t[Nh][t], bias_t[Nh][t], bias_t[Nh][t], bias_t[Nh][t]};

    // ---- independent half (no barrier dependency): layer0 x-part ----
    if (isA && active) {
      bf16x8 af[8];
      if (USE_XB) {
        const unsigned short* xp = xb + ((((size_t)p * 8 + wv) * 8) * 64 + lane) * 8;
#pragma unroll
        for (int kt = 0; kt < 8; ++kt)
          af[kt] = *(const bf16x8*)(xp + (size_t)kt * 64 * 8);
      } else {
        const float* xp0 = x + (((size_t)(wv * 16 + c15)) * SEQ + p) * DIN + q * 8;
#pragma unroll
        for (int kt = 0; kt < 8; ++kt) {
          f32x4 a = *(const f32x4*)(xp0 + kt * 32);
          f32x4 b = *(const f32x4*)(xp0 + kt * 32 + 4);
          af[kt][0] = (short)f2bf(a[0]); af[kt][1] = (short)f2bf(a[1]);
          af[kt][2] = (short)f2bf(a[2]); af[kt][3] = (short)f2bf(a[3]);
          af[kt][4] = (short)f2bf(b[0]); af[kt][5] = (short)f2bf(b[1]);
          af[kt][6] = (short)f2bf(b[2]); af[kt][7] = (short)f2bf(b[3]);
        }
      }
#pragma unroll
      for (int kt = 0; kt < 8; ++kt)
#pragma unroll
        for (int Nh = 0; Nh < 2; ++Nh)
#pragma unroll
          for (int t = 0; t < 2; ++t) {
            bf16x8 bf = *(const bf16x8*)&smem[(Nh * 32 + t * 16 + c15) * LDKA + kt * 32 + q * 8];
            acc[Nh][t] = __builtin_amdgcn_mfma_f32_16x16x32_bf16(af[kt], bf, acc[Nh][t], 0, 0, 0);
          }
    }

    // ---- wait for slot p-1 publication: relaxed poll, single acquire ----
    __syncthreads();
    if (tid == 0 && p > 0) {
      unsigned int target = (unsigned int)p * NWG;
      while (__hip_atomic_load(bar_cnt, __ATOMIC_RELAXED, __HIP_MEMORY_SCOPE_AGENT) < target)
        __builtin_amdgcn_s_sleep(1);
      (void)__hip_atomic_load(bar_cnt, __ATOMIC_ACQUIRE, __HIP_MEMORY_SCOPE_AGENT);  // buffer_inv once
    }
    __syncthreads();

    // ---- dependent half ----
    if (active) {
      if (isA) {
        bf16x8 ah[16];  // h0(p-1), kt 8..23
        const unsigned short* hp = h0rd + ((size_t)wv * 16 * 64) * 8 + (size_t)lane * 8;
#pragma unroll
        for (int i = 0; i < 16; ++i)
          ah[i] = *(const bf16x8*)(hp + (size_t)i * 64 * 8);
#pragma unroll
        for (int i = 0; i < 16; ++i) {
          int kt = 8 + i;
#pragma unroll
          for (int Nh = 0; Nh < 2; ++Nh)
#pragma unroll
            for (int t = 0; t < 2; ++t) {
              bf16x8 bf = *(const bf16x8*)&smem[(Nh * 32 + t * 16 + c15) * LDKA + kt * 32 + q * 8];
              acc[Nh][t] = __builtin_amdgcn_mfma_f32_16x16x32_bf16(ah[i], bf, acc[Nh][t], 0, 0, 0);
            }
        }
      } else {
        bf16x8 a0[16], a1[16];  // h0(p-1) -> kt 0..15 ; h1(p-2) -> kt 16..31
        const unsigned short* hp0 = h0rd + ((size_t)wv * 16 * 64) * 8 + (size_t)lane * 8;
        const unsigned short* hp1 = h1rd + ((size_t)wv * 16 * 64) * 8 + (size_t)lane * 8;
#pragma unroll
        for (int i = 0; i < 16; ++i)
          a0[i] = *(const bf16x8*)(hp0 + (size_t)i * 64 * 8);
#pragma unroll
        for (int i = 0; i < 16; ++i)
          a1[i] = *(const bf16x8*)(hp1 + (size_t)i * 64 * 8);
#pragma unroll
        for (int i = 0; i < 16; ++i)
#pragma unroll
          for (int Nh = 0; Nh < 2; ++Nh)
#pragma unroll
            for (int t = 0; t < 2; ++t) {
              bf16x8 bf = *(const bf16x8*)&smem[(Nh * 32 + t * 16 + c15) * LDKB + i * 32 + q * 8];
              acc[Nh][t] = __builtin_amdgcn_mfma_f32_16x16x32_bf16(a0[i], bf, acc[Nh][t], 0, 0, 0);
            }
#pragma unroll
        for (int i = 0; i < 16; ++i) {
          int kt = 16 + i;
#pragma unroll
          for (int Nh = 0; Nh < 2; ++Nh)
#pragma unroll
            for (int t = 0; t < 2; ++t) {
              bf16x8 bf = *(const bf16x8*)&smem[(Nh * 32 + t * 16 + c15) * LDKB + kt * 32 + q * 8];
              acc[Nh][t] = __builtin_amdgcn_mfma_f32_16x16x32_bf16(a1[i], bf, acc[Nh][t], 0, 0, 0);
            }
        }
      }

      // ---- gates; stage h tile (128 rows x 16 units) in LDS ----
#pragma unroll
      for (int Nh = 0; Nh < 2; ++Nh) {
#pragma unroll
        for (int r = 0; r < 4; ++r) {
          float aif = acc[Nh][0][r], ago = acc[Nh][1][r];
          float pif = __shfl_xor(aif, 8);
          float pgo = __shfl_xor(ago, 8);
          if (s == 0) {
            float cn = sigmoidf_fast(pif) * cst[Nh][r] +
                       sigmoidf_fast(aif) * tanhf_fast(ago);
            cst[Nh][r] = cn;
            float hn = sigmoidf_fast(pgo) * tanhf_fast(cn);
            int row = wv * 16 + q * 4 + r;
            stage[row * 16 + Nh * 8 + u] = f2bf(hn);
            if (!isA && p == NSLOT - 1)
              h1fin[(size_t)row * HID + unit0 + Nh * 8 + u] = hn;
          }
        }
      }
    }
    __syncthreads();

    // ---- cooperative fragment-layout publish (coalesced, non-temporal) ----
    if (active && tid < 256) {
      int mi2 = tid >> 5, qq = (tid >> 4) & 1, r15 = tid & 15;
      int row = mi2 * 16 + r15;
      ushort8 v = *(const ushort8*)&stage[row * 16 + qq * 8];
      unsigned short* dst = (isA ? h0wr : h1wr) +
          (((size_t)mi2 * 16 + kt0) * 64 + (qbase + qq) * 16 + r15) * 8;
      __builtin_nontemporal_store(v, (ushort8*)dst);
    }
    __syncthreads();  // vmcnt drain: stores in L2 before leader's release

    if (tid == 0)
      __hip_atomic_fetch_add(bar_cnt, 1u, __ATOMIC_RELEASE, __HIP_MEMORY_SCOPE_AGENT);
  }
}

__global__ __launch_bounds__(256) void proj_kernel(
    const float* __restrict__ h1, const float* __restrict__ Wp,
    const float* __restrict__ bp, float* __restrict__ out)
{
  int o = blockIdx.x * 256 + threadIdx.x;
  int b = blockIdx.y;
  if (o >= OUTD) return;
  const float* hr = h1 + (size_t)b * HID;
  float acc = bp[o];
#pragma unroll 8
  for (int k = 0; k < HID; ++k)
    acc = fmaf(hr[k], Wp[(size_t)k * OUTD + o], acc);
  out[(size_t)b * OUTD + o] = acc;
}

extern "C" void kernel_launch(void* const* d_in, const int* in_sizes, int n_in,
                              void* d_out, int out_size, void* d_ws, size_t ws_size,
                              hipStream_t stream) {
  const float* x  = (const float*)d_in[0];
  const float* W0 = (const float*)d_in[1];
  const float* b0 = (const float*)d_in[2];
  const float* W1 = (const float*)d_in[3];
  const float* b1 = (const float*)d_in[4];
  const float* Wp = (const float*)d_in[5];
  const float* bp = (const float*)d_in[6];
  float* out = (float*)d_out;

  char* ws = (char*)d_ws;
  unsigned int* cnt   = (unsigned int*)ws;                        // 4 KB
  unsigned short* h0b = (unsigned short*)(ws + 4096);             // 256 KB
  unsigned short* h1b = (unsigned short*)(ws + 4096 + 262144);    // 256 KB
  float* h1fin        = (float*)(ws + 4096 + 2 * 262144);         // 256 KB
  unsigned short* xbp = (unsigned short*)(ws + 4096 + 3 * 262144);// 32 MB
  const size_t need_xb = 4096 + 3 * 262144 + (size_t)SEQ * BATCH * DIN * 2;
  const bool use_xb = (ws_size >= need_xb);

  hipMemsetAsync(d_ws, 0, 4096 + 2 * 262144, stream);
  if (use_xb) {
    hipLaunchKernelGGL(xprep, dim3(SEQ), dim3(256), 0, stream, x, xbp);
    hipLaunchKernelGGL(lstm_persistent<true>, dim3(NWG), dim3(TPB), 0, stream,
                       x, xbp, W0, b0, W1, b1, cnt, h0b, h1b, h1fin);
  } else {
    hipLaunchKernelGGL(lstm_persistent<false>, dim3(NWG), dim3(TPB), 0, stream,
                       x, xbp, W0, b0, W1, b1, cnt, h0b, h1b, h1fin);
  }
  hipLaunchKernelGGL(proj_kernel, dim3((OUTD + 255) / 256, BATCH), dim3(256), 0, stream,
                     h1fin, Wp, bp, out);
}